// Round 20
// baseline (209.469 us; speedup 1.0000x reference)
//
#include <hip/hip_runtime.h>
#include <cstdint>
#include <cstddef>

#define NN 50000
#define NE 800000
#define RREL 5
#define NR (NN * RREL)                 // 250000 (dst,type) keys
#define NB5 ((NR + 255) / 256)         // 977

typedef __attribute__((ext_vector_type(8))) short short8;   // 8 bf16 (4 VGPRs)
typedef __attribute__((ext_vector_type(4))) float f32x4;
typedef unsigned short ushort_t;

static __device__ __forceinline__ float lrelu(float v) { return v > 0.f ? v : 0.01f * v; }

static __device__ __forceinline__ unsigned short f32_bf16_rn(float x) {
    unsigned u = __float_as_uint(x);
    return (unsigned short)((u + 0x7FFFu + ((u >> 16) & 1u)) >> 16);
}
static __device__ __forceinline__ float bf16_f32(unsigned short h) {
    return __uint_as_float(((unsigned)h) << 16);
}

// split 8 f32 (two float4) into bf16 hi + lo (x ~= hi + lo)
static __device__ __forceinline__ void split8v(float4 q0, float4 q1, short8& hi, short8& lo) {
    float v[8] = {q0.x, q0.y, q0.z, q0.w, q1.x, q1.y, q1.z, q1.w};
    #pragma unroll
    for (int j = 0; j < 8; ++j) {
        unsigned short h = f32_bf16_rn(v[j]);
        float hf = __uint_as_float(((unsigned)h) << 16);
        unsigned short l = f32_bf16_rn(v[j] - hf);
        hi[j] = (short)h; lo[j] = (short)l;
    }
}

static __device__ __forceinline__ short8 zero8() {
    short8 z = {0, 0, 0, 0, 0, 0, 0, 0};
    return z;
}

// ---------------------------------------------------------------------------
// zero_deg5: fast workspace zeroing
// ---------------------------------------------------------------------------
__launch_bounds__(256)
__global__ void zero_deg5(int4* __restrict__ p, int n4)
{
    int i = blockIdx.x * 256 + threadIdx.x;
    int stride = gridDim.x * 256;
    for (; i < n4; i += stride)
        p[i] = make_int4(0, 0, 0, 0);
}

// ---------------------------------------------------------------------------
// lin_mfma: e0b = bf16(x @ field_W + field_b)  (K=128)
// ---------------------------------------------------------------------------
__launch_bounds__(512)
__global__ void lin_mfma(const float* __restrict__ X,
                         const short8* __restrict__ ff,   // [16][64] hi frags
                         const float* __restrict__ bias,
                         ushort_t* __restrict__ Cb, int M)
{
    __shared__ short8 wl[16 * 64];   // 16 KB

    const int t = threadIdx.x;
    const int wid = t >> 6, lane = t & 63;
    const int lc = lane & 15, lg = lane >> 4;
    const int row0 = blockIdx.x * 128 + wid * 16;

    const int nA = row0 + lc;
    const bool okA = (nA < M);
    const int nodeA = okA ? nA : 0;

    wl[t] = ff[t];
    wl[t + 512] = ff[t + 512];

    short8 ah[4], al[4];
    #pragma unroll
    for (int s = 0; s < 4; ++s) {
        const float* p = &X[(size_t)nodeA * 128 + s * 32 + lg * 8];
        float4 q0 = okA ? *(const float4*)p       : make_float4(0,0,0,0);
        float4 q1 = okA ? *(const float4*)(p + 4) : make_float4(0,0,0,0);
        split8v(q0, q1, ah[s], al[s]);
    }
    __syncthreads();

    f32x4 acc[4];
    #pragma unroll
    for (int nf = 0; nf < 4; ++nf) acc[nf] = (f32x4){0.f, 0.f, 0.f, 0.f};

    #pragma unroll
    for (int s = 0; s < 4; ++s)
        #pragma unroll
        for (int nf = 0; nf < 4; ++nf) {
            short8 bh = wl[(s * 4 + nf) * 64 + lane];
            acc[nf] = __builtin_amdgcn_mfma_f32_16x16x32_bf16(ah[s], bh, acc[nf], 0, 0, 0);
            acc[nf] = __builtin_amdgcn_mfma_f32_16x16x32_bf16(al[s], bh, acc[nf], 0, 0, 0);
        }

    float bb[4];
    #pragma unroll
    for (int nf = 0; nf < 4; ++nf) bb[nf] = bias[nf * 16 + lc];

    #pragma unroll
    for (int i = 0; i < 4; ++i) {
        int nd = row0 + lg * 4 + i;
        if (nd >= M) continue;
        #pragma unroll
        for (int nf = 0; nf < 4; ++nf)
            Cb[(size_t)nd * 64 + nf * 16 + lc] = f32_bf16_rn(acc[nf][i] + bb[nf]);
    }
}

// ---------------------------------------------------------------------------
// head_mfma: out = sum_src lrelu(Eb_src @ W_src + b_src)
// ---------------------------------------------------------------------------
__launch_bounds__(512)
__global__ void head_mfma(const ushort_t* __restrict__ E0, const ushort_t* __restrict__ E1,
                          const ushort_t* __restrict__ E2,
                          const short8* __restrict__ hf,   // [3][8][64] hi frags
                          const float* __restrict__ b0, const float* __restrict__ b1,
                          const float* __restrict__ b2,
                          float* __restrict__ out, int M)
{
    __shared__ short8 wl[24 * 64];   // 24 KB

    const int t = threadIdx.x;
    const int wid = t >> 6, lane = t & 63;
    const int lc = lane & 15, lg = lane >> 4;
    const int row0 = blockIdx.x * 128 + wid * 16;

    const int nA = row0 + lc;
    const bool okA = (nA < M);
    const int nodeA = okA ? nA : 0;

    wl[t] = hf[t];
    wl[t + 512] = hf[t + 512];
    wl[t + 1024] = hf[t + 1024];

    const ushort_t* Es[3] = {E0, E1, E2};
    const float* bs[3] = {b0, b1, b2};

    float facc[4][4] = {};   // [nf][i]
    __syncthreads();

    #pragma unroll
    for (int src = 0; src < 3; ++src) {
        short8 ah[2];
        #pragma unroll
        for (int s = 0; s < 2; ++s) {
            const ushort_t* p = &Es[src][(size_t)nodeA * 64 + s * 32 + lg * 8];
            ah[s] = okA ? *(const short8*)p : zero8();
        }
        f32x4 acc[4];
        #pragma unroll
        for (int nf = 0; nf < 4; ++nf) acc[nf] = (f32x4){0.f, 0.f, 0.f, 0.f};
        #pragma unroll
        for (int s = 0; s < 2; ++s)
            #pragma unroll
            for (int nf = 0; nf < 4; ++nf) {
                short8 bh = wl[((src * 2 + s) * 4 + nf) * 64 + lane];
                acc[nf] = __builtin_amdgcn_mfma_f32_16x16x32_bf16(ah[s], bh, acc[nf], 0, 0, 0);
            }
        float bb[4];
        #pragma unroll
        for (int nf = 0; nf < 4; ++nf) bb[nf] = bs[src][nf * 16 + lc];
        #pragma unroll
        for (int nf = 0; nf < 4; ++nf)
            #pragma unroll
            for (int i = 0; i < 4; ++i)
                facc[nf][i] += lrelu(acc[nf][i] + bb[nf]);
    }

    #pragma unroll
    for (int i = 0; i < 4; ++i) {
        int nd = row0 + lg * 4 + i;
        if (nd >= M) continue;
        #pragma unroll
        for (int nf = 0; nf < 4; ++nf)
            out[(size_t)nd * 64 + nf * 16 + lc] = facc[nf][i];
    }
}

// ---------------------------------------------------------------------------
// zgather v10: one wave walks FOUR consecutive nodes' contiguous edge stream
// (20 segments). Segment flushes are data-driven via marker bits embedded by
// scatter_pass: lo32 = src(17b) | rel_seg(5b)<<17 | last_of_seg(1b)<<22.
// Empty segments zero-filled from rel_seg gaps. 8 edges in flight.
// ---------------------------------------------------------------------------
__launch_bounds__(256)
__global__ void zgather(const int* __restrict__ offs5,
                        const unsigned long long* __restrict__ epack,
                        const ushort_t* __restrict__ Eb,
                        ushort_t* __restrict__ Zb16, float* __restrict__ S)
{
    int gw = (blockIdx.x * 256 + threadIdx.x) >> 6;   // wave id
    int lane = threadIdx.x & 63;
    int nbase = gw * 4;
    if (nbase >= NN) return;
    const int bstart = nbase * RREL;
    const int bcount = (NR - bstart < 4 * RREL) ? (NR - bstart) : (4 * RREL);

    int p    = offs5[bstart];
    int pend = offs5[bstart + bcount];

    float z = 0.f, sw = 0.f;
    int lastf = -1;

#define WVAL(q64) __uint_as_float((unsigned)((q64) >> 32))

#define STEP(q64, v)                                                        \
    {                                                                       \
        unsigned lo = (unsigned)(q64);                                      \
        float w = WVAL(q64);                                                \
        z = fmaf(w, v, z); sw += w;                                         \
        if (lo & (1u << 22)) {                                              \
            int rs = (int)((lo >> 17) & 31u);                               \
            for (int j = lastf + 1; j < rs; ++j) {                          \
                Zb16[(size_t)(bstart + j) * 64 + lane] = 0;                 \
                if (lane == 0) S[bstart + j] = 0.f;                         \
            }                                                               \
            Zb16[(size_t)(bstart + rs) * 64 + lane] = f32_bf16_rn(z);       \
            if (lane == 0) S[bstart + rs] = sw;                             \
            z = 0.f; sw = 0.f; lastf = rs;                                  \
        }                                                                   \
    }

    for (; p + 8 <= pend; p += 8) {
        unsigned long long q0 = epack[p + 0];
        unsigned long long q1 = epack[p + 1];
        unsigned long long q2 = epack[p + 2];
        unsigned long long q3 = epack[p + 3];
        unsigned long long q4 = epack[p + 4];
        unsigned long long q5 = epack[p + 5];
        unsigned long long q6 = epack[p + 6];
        unsigned long long q7 = epack[p + 7];
        float v0 = bf16_f32(Eb[(size_t)((unsigned)q0 & 0x1FFFFu) * 64 + lane]);
        float v1 = bf16_f32(Eb[(size_t)((unsigned)q1 & 0x1FFFFu) * 64 + lane]);
        float v2 = bf16_f32(Eb[(size_t)((unsigned)q2 & 0x1FFFFu) * 64 + lane]);
        float v3 = bf16_f32(Eb[(size_t)((unsigned)q3 & 0x1FFFFu) * 64 + lane]);
        float v4 = bf16_f32(Eb[(size_t)((unsigned)q4 & 0x1FFFFu) * 64 + lane]);
        float v5 = bf16_f32(Eb[(size_t)((unsigned)q5 & 0x1FFFFu) * 64 + lane]);
        float v6 = bf16_f32(Eb[(size_t)((unsigned)q6 & 0x1FFFFu) * 64 + lane]);
        float v7 = bf16_f32(Eb[(size_t)((unsigned)q7 & 0x1FFFFu) * 64 + lane]);

        STEP(q0, v0);
        STEP(q1, v1);
        STEP(q2, v2);
        STEP(q3, v3);
        STEP(q4, v4);
        STEP(q5, v5);
        STEP(q6, v6);
        STEP(q7, v7);
    }
    for (; p < pend; ++p) {
        unsigned long long q = epack[p];
        float v = bf16_f32(Eb[(size_t)((unsigned)q & 0x1FFFFu) * 64 + lane]);
        STEP(q, v);
    }
    // drain: zero-fill any remaining empty segments
    for (int j = lastf + 1; j < bcount; ++j) {
        Zb16[(size_t)(bstart + j) * 64 + lane] = 0;
        if (lane == 0) S[bstart + j] = 0.f;
    }
#undef STEP
#undef WVAL
}

// ---------------------------------------------------------------------------
// prep_wfrag: weight fragment prep (rel hi+lo; field hi; head hi).
// ---------------------------------------------------------------------------
__launch_bounds__(256)
__global__ void prep_wfrag(const float* __restrict__ rel1_W, const float* __restrict__ rel2_W,
                           const float* __restrict__ field_W,
                           const float* __restrict__ out0_W, const float* __restrict__ out1_W,
                           const float* __restrict__ out2_W,
                           short8* __restrict__ wf1, short8* __restrict__ wf2,
                           short8* __restrict__ ff, short8* __restrict__ hf)
{
    int bid = blockIdx.x;
    int t = threadIdx.x;

    if (bid < 20) {
        int layer = bid / 10, c = bid % 10;
        const float* relW = layer ? rel2_W : rel1_W;
        short8* wf = layer ? wf2 : wf1;
        for (int sl = t; sl < 512; sl += 256) {
            int rid = sl >> 6, lane = sl & 63;
            int s = rid >> 2, nf = rid & 3;
            int g = lane >> 4, lc = lane & 15;
            int r = (c < 5) ? c : c - 5;
            const float* W = relW + (size_t)r * 8192 + ((c < 5) ? 0 : 4096);
            float v[8];
            #pragma unroll
            for (int j = 0; j < 8; ++j)
                v[j] = W[(size_t)(s * 32 + g * 8 + j) * 64 + nf * 16 + lc];
            float4 q0 = make_float4(v[0], v[1], v[2], v[3]);
            float4 q1 = make_float4(v[4], v[5], v[6], v[7]);
            short8 hi, lo;
            split8v(q0, q1, hi, lo);
            size_t slot = (size_t)c * 1024 + (size_t)((s * 4 + nf) * 64 + lane) * 2;
            wf[slot]     = hi;
            wf[slot + 1] = lo;
        }
    } else if (bid < 24) {
        int s = bid - 20;             // K-slice 0..3
        for (int sl = t; sl < 256; sl += 256) {
            int nf = sl >> 6, lane = sl & 63;
            int g = lane >> 4, lc = lane & 15;
            float v[8];
            #pragma unroll
            for (int j = 0; j < 8; ++j)
                v[j] = field_W[(size_t)(s * 32 + g * 8 + j) * 64 + nf * 16 + lc];
            short8 hi;
            #pragma unroll
            for (int j = 0; j < 8; ++j) hi[j] = (short)f32_bf16_rn(v[j]);
            ff[(size_t)(s * 4 + nf) * 64 + lane] = hi;
        }
    } else {
        int hsrc = bid - 24;          // 0..2
        const float* W = (hsrc == 0) ? out0_W : (hsrc == 1) ? out1_W : out2_W;
        for (int sl = t; sl < 512; sl += 256) {
            int rid = sl >> 6, lane = sl & 63;
            int s = rid >> 2, nf = rid & 3;
            if (s >= 2) continue;
            int g = lane >> 4, lc = lane & 15;
            float v[8];
            #pragma unroll
            for (int j = 0; j < 8; ++j)
                v[j] = W[(size_t)(s * 32 + g * 8 + j) * 64 + nf * 16 + lc];
            short8 hi;
            #pragma unroll
            for (int j = 0; j < 8; ++j) hi[j] = (short)f32_bf16_rn(v[j]);
            hf[(size_t)((hsrc * 2 + s) * 4 + nf) * 64 + lane] = hi;
        }
    }
}

// ---------------------------------------------------------------------------
// zgemm_mfma v4: all-bf16 features; Z + e_prev direct fragments.
// ---------------------------------------------------------------------------
__launch_bounds__(512)
__global__ void zgemm_mfma(const ushort_t* __restrict__ Zb16,
                           const ushort_t* __restrict__ EbPrev,
                           const short8* __restrict__ wf,
                           const float* __restrict__ relb,
                           const float* __restrict__ S,
                           ushort_t* __restrict__ Enb, int M)
{
    __shared__ short8 wlds[2][1024];   // 2 x 16 KB

    const int t = threadIdx.x;
    const int wid = t >> 6, lane = t & 63;
    const int lc = lane & 15, lg = lane >> 4;
    const int row0 = blockIdx.x * 128 + wid * 16;

    const int nA = row0 + lc;
    const bool okA = (nA < M);
    const int nodeA = okA ? nA : 0;

    const int sq = t >> 6, sl = t & 63;
    const int wrA = (sq * 2 + 0) * 64 + sl;
    const int wrB = (sq * 2 + 1) * 64 + sl;

    short8 eh[2];
    #pragma unroll
    for (int s = 0; s < 2; ++s) {
        const ushort_t* p = &EbPrev[(size_t)nodeA * 64 + s * 32 + lg * 8];
        eh[s] = okA ? *(const short8*)p : zero8();
    }

    float sD[4][RREL];
    #pragma unroll
    for (int i = 0; i < 4; ++i) {
        int nd = row0 + lg * 4 + i;
        int ns = (nd < M) ? nd : 0;
        #pragma unroll
        for (int r = 0; r < RREL; ++r)
            sD[i][r] = S[(size_t)ns * RREL + r];
    }

    {
        const short8* wp = wf + (size_t)t * 2;
        short8 sa = wp[0], sb = wp[1];
        wlds[0][wrA] = sa; wlds[0][wrB] = sb;
    }
    short8 az0, az1;
    {
        const ushort_t* zb = &Zb16[(size_t)nodeA * 320 + lg * 8];
        az0 = okA ? *(const short8*)(zb)      : zero8();
        az1 = okA ? *(const short8*)(zb + 32) : zero8();
    }
    __syncthreads();

    f32x4 acc[4];
    #pragma unroll
    for (int nf = 0; nf < 4; ++nf) acc[nf] = (f32x4){0.f, 0.f, 0.f, 0.f};

    short8 sreg_a, sreg_b;
    short8 pz0, pz1;

    #pragma unroll
    for (int c = 0; c < 10; ++c) {
        const int cb = c & 1;
        if (c < 9) {
            const short8* wp = wf + (size_t)(c + 1) * 1024 + (size_t)t * 2;
            sreg_a = wp[0]; sreg_b = wp[1];
        }
        if (c < 4) {
            const ushort_t* zb = &Zb16[(size_t)nodeA * 320 + (c + 1) * 64 + lg * 8];
            pz0 = okA ? *(const short8*)(zb)      : zero8();
            pz1 = okA ? *(const short8*)(zb + 32) : zero8();
        }

        if (c < 5) {
            #pragma unroll
            for (int s = 0; s < 2; ++s) {
                short8 Az = (s == 0) ? az0 : az1;
                #pragma unroll
                for (int nf = 0; nf < 4; ++nf) {
                    short8 bh = wlds[cb][((s * 4 + nf) * 2 + 0) * 64 + lane];
                    short8 bl = wlds[cb][((s * 4 + nf) * 2 + 1) * 64 + lane];
                    acc[nf] = __builtin_amdgcn_mfma_f32_16x16x32_bf16(Az, bh, acc[nf], 0, 0, 0);
                    acc[nf] = __builtin_amdgcn_mfma_f32_16x16x32_bf16(Az, bl, acc[nf], 0, 0, 0);
                }
            }
        } else {
            f32x4 tmp[4];
            #pragma unroll
            for (int nf = 0; nf < 4; ++nf) tmp[nf] = (f32x4){0.f, 0.f, 0.f, 0.f};
            #pragma unroll
            for (int s = 0; s < 2; ++s)
                #pragma unroll
                for (int nf = 0; nf < 4; ++nf) {
                    short8 bh = wlds[cb][((s * 4 + nf) * 2 + 0) * 64 + lane];
                    short8 bl = wlds[cb][((s * 4 + nf) * 2 + 1) * 64 + lane];
                    tmp[nf] = __builtin_amdgcn_mfma_f32_16x16x32_bf16(eh[s], bh, tmp[nf], 0, 0, 0);
                    tmp[nf] = __builtin_amdgcn_mfma_f32_16x16x32_bf16(eh[s], bl, tmp[nf], 0, 0, 0);
                }
            const int r = c - 5;
            #pragma unroll
            for (int nf = 0; nf < 4; ++nf)
                #pragma unroll
                for (int i = 0; i < 4; ++i)
                    acc[nf][i] += sD[i][r] * tmp[nf][i];
        }

        if (c < 4) { az0 = pz0; az1 = pz1; }

        if (c < 9) {
            __syncthreads();
            wlds[cb ^ 1][wrA] = sreg_a;
            wlds[cb ^ 1][wrB] = sreg_b;
            __syncthreads();
        }
    }

    float bbv[4][RREL];
    #pragma unroll
    for (int nf = 0; nf < 4; ++nf)
        #pragma unroll
        for (int r = 0; r < RREL; ++r)
            bbv[nf][r] = relb[r * 64 + nf * 16 + lc];

    #pragma unroll
    for (int i = 0; i < 4; ++i) {
        int nd = row0 + lg * 4 + i;
        if (nd >= M) continue;
        #pragma unroll
        for (int nf = 0; nf < 4; ++nf) {
            float v = acc[nf][i];
            #pragma unroll
            for (int r = 0; r < RREL; ++r)
                v += sD[i][r] * bbv[nf][r];
            Enb[(size_t)nd * 64 + nf * 16 + lc] = f32_bf16_rn(v);
        }
    }
}

// ---------------------------------------------------------------------------
// CSR build over (dst,type) keys
// ---------------------------------------------------------------------------
__launch_bounds__(256)
__global__ void deg5_hist(const int* __restrict__ dst, const int* __restrict__ etype,
                          int* __restrict__ deg5, int* __restrict__ slot5)
{
    int e = blockIdx.x * 256 + threadIdx.x;
    if (e < NE) slot5[e] = atomicAdd(&deg5[dst[e] * RREL + etype[e]], 1);
}

__launch_bounds__(256)
__global__ void b1_reduce(const int* __restrict__ deg5, int* __restrict__ b1)
{
    __shared__ int sh[256];
    int i = blockIdx.x * 256 + threadIdx.x;
    sh[threadIdx.x] = (i < NR) ? deg5[i] : 0;
    __syncthreads();
    for (int s = 128; s > 0; s >>= 1) {
        if (threadIdx.x < s) sh[threadIdx.x] += sh[threadIdx.x + s];
        __syncthreads();
    }
    if (threadIdx.x == 0) b1[blockIdx.x] = sh[0];
}

__launch_bounds__(256)
__global__ void scan_seq(int* __restrict__ b1, int n)
{
    __shared__ int sh[256];
    __shared__ int carry;
    if (threadIdx.x == 0) carry = 0;
    __syncthreads();
    for (int base = 0; base < n; base += 256) {
        int i = base + threadIdx.x;
        int v = (i < n) ? b1[i] : 0;
        sh[threadIdx.x] = v;
        __syncthreads();
        for (int off = 1; off < 256; off <<= 1) {
            int x = (threadIdx.x >= off) ? sh[threadIdx.x - off] : 0;
            __syncthreads();
            sh[threadIdx.x] += x;
            __syncthreads();
        }
        int excl = sh[threadIdx.x] - v + carry;
        if (i < n) b1[i] = excl;
        __syncthreads();
        if (threadIdx.x == 255) carry = excl + v;
        __syncthreads();
    }
}

__launch_bounds__(256)
__global__ void offs5_final(const int* __restrict__ deg5, const int* __restrict__ b1,
                            int* __restrict__ offs5)
{
    __shared__ int sh[256];
    int t = threadIdx.x;
    int i = blockIdx.x * 256 + t;
    int v = (i < NR) ? deg5[i] : 0;
    sh[t] = v;
    __syncthreads();
    for (int off = 1; off < 256; off <<= 1) {
        int x = (t >= off) ? sh[t - off] : 0;
        __syncthreads();
        sh[t] += x;
        __syncthreads();
    }
    int excl = sh[t] - v + b1[blockIdx.x];
    if (i <= NR) offs5[i] = excl;
}

// scatter: epack[offs5[key] + slot5[e]] = {w, src|relseg|marker}
__launch_bounds__(256)
__global__ void scatter_pass(const int* __restrict__ src, const int* __restrict__ dst,
                             const int* __restrict__ etype,
                             const float* __restrict__ etime,
                             const float* __restrict__ beta,
                             const float* __restrict__ lambda_p,
                             const int* __restrict__ slot5, const int* __restrict__ offs5,
                             const int* __restrict__ deg5,
                             unsigned long long* __restrict__ epack)
{
    int e = blockIdx.x * 256 + threadIdx.x;
    if (e >= NE) return;
    float b[12];
    #pragma unroll
    for (int j = 0; j < 12; ++j) b[j] = beta[j];
    const float* et = etime + (size_t)e * 12;
    float4 v0 = *(const float4*)(et);
    float4 v1 = *(const float4*)(et + 4);
    float4 v2 = *(const float4*)(et + 8);
    float logit = v0.x*b[0] + v0.y*b[1] + v0.z*b[2] + v0.w*b[3]
                + v1.x*b[4] + v1.y*b[5] + v1.z*b[6] + v1.w*b[7]
                + v2.x*b[8] + v2.y*b[9] + v2.z*b[10] + v2.w*b[11];
    float we = lambda_p[0] * expf(-logit);
    int d = dst[e], r = etype[e];
    int key = d * RREL + r;
    int sl = slot5[e];
    unsigned marker = (sl + 1 == deg5[key]) ? (1u << 22) : 0u;
    unsigned relseg = (unsigned)((d & 3) * RREL + r) << 17;   // wave covers 4 nodes
    unsigned lo = (unsigned)src[e] | relseg | marker;
    int p = offs5[key] + sl;
    epack[p] = ((unsigned long long)__float_as_uint(we) << 32) | lo;
}

// ---------------------------------------------------------------------------
extern "C" void kernel_launch(void* const* d_in, const int* in_sizes, int n_in,
                              void* d_out, int out_size, void* d_ws, size_t ws_size,
                              hipStream_t stream)
{
    const float* x        = (const float*)d_in[0];
    const int*   eidx     = (const int*)d_in[1];
    const int*   etype    = (const int*)d_in[2];
    const float* etime    = (const float*)d_in[3];
    const float* lambda_p = (const float*)d_in[4];
    const float* beta     = (const float*)d_in[5];
    const float* field_W  = (const float*)d_in[6];
    const float* field_b  = (const float*)d_in[7];
    const float* rel1_W   = (const float*)d_in[8];
    const float* rel1_b   = (const float*)d_in[9];
    const float* rel2_W   = (const float*)d_in[10];
    const float* rel2_b   = (const float*)d_in[11];
    const float* out0_W   = (const float*)d_in[12];
    const float* out0_b   = (const float*)d_in[13];
    const float* out1_W   = (const float*)d_in[14];
    const float* out1_b   = (const float*)d_in[15];
    const float* out2_W   = (const float*)d_in[16];
    const float* out2_b   = (const float*)d_in[17];
    const int* src = eidx;
    const int* dst = eidx + NE;
    float* out = (float*)d_out;

    char* wsb = (char*)d_ws;
    size_t off = 0;
    auto carve = [&](size_t bytes) -> void* {
        void* p = (void*)(wsb + off);
        off += (bytes + 255) & ~(size_t)255;
        return p;
    };
    int*   deg5   = (int*)carve((size_t)NR * 4);            // 1 MB
    int*   offs5  = (int*)carve((size_t)(NR + 1) * 4);      // 1 MB
    int*   b1     = (int*)carve((size_t)NB5 * 4);
    int*   slot5  = (int*)carve((size_t)NE * 4);            // 3.2 MB
    float* S      = (float*)carve((size_t)NR * 4);          // 1 MB
    unsigned long long* epack = (unsigned long long*)carve((size_t)NE * 8); // 6.4 MB
    ushort_t* e0b = (ushort_t*)carve((size_t)NN * 64 * 2);  // 6.4 MB bf16
    ushort_t* e1b = (ushort_t*)carve((size_t)NN * 64 * 2);  // 6.4 MB bf16
    ushort_t* e2b = (ushort_t*)carve((size_t)NN * 64 * 2);  // 6.4 MB bf16
    ushort_t* Zb16 = (ushort_t*)carve((size_t)NN * 320 * 2); // 32 MB bf16 Z
    short8* wf1   = (short8*)carve((size_t)20 * 16384);     // 320 KB
    short8* wf2   = (short8*)carve((size_t)20 * 16384);     // 320 KB
    short8* ff    = (short8*)carve((size_t)16 * 64 * 16);   // 16 KB field frags
    short8* hf    = (short8*)carve((size_t)24 * 64 * 16);   // 24 KB head frags

    dim3 blk(256);
    const int NT128 = (NN + 127) / 128;     // 391
    const int EB = (NE + 255) / 256;
    const int NW4 = (NN + 3) / 4;           // waves (4 nodes each) = 12500
    const int GB4 = (NW4 * 64 + 255) / 256; // 3125 blocks

    // ---- CSR build over (dst,type) + weight frag prep ----
    zero_deg5<<<256, blk, 0, stream>>>((int4*)deg5, (NR + 3) / 4);
    deg5_hist<<<EB, blk, 0, stream>>>(dst, etype, deg5, slot5);
    prep_wfrag<<<27, blk, 0, stream>>>(rel1_W, rel2_W, field_W, out0_W, out1_W, out2_W,
                                       wf1, wf2, ff, hf);
    b1_reduce<<<NB5, blk, 0, stream>>>(deg5, b1);
    scan_seq<<<1, blk, 0, stream>>>(b1, NB5);
    offs5_final<<<NB5, blk, 0, stream>>>(deg5, b1, offs5);
    scatter_pass<<<EB, blk, 0, stream>>>(src, dst, etype, etime, beta, lambda_p,
                                         slot5, offs5, deg5, epack);

    // ---- e0b = bf16(x @ field_W + field_b) ----
    lin_mfma<<<dim3(NT128), dim3(512), 0, stream>>>(x, ff, field_b, e0b, NN);

    // ---- layer 1 ----
    zgather<<<GB4, blk, 0, stream>>>(offs5, epack, e0b, Zb16, S);
    zgemm_mfma<<<dim3(NT128), dim3(512), 0, stream>>>(Zb16, e0b, wf1, rel1_b, S, e1b, NN);

    // ---- layer 2 ----
    zgather<<<GB4, blk, 0, stream>>>(offs5, epack, e1b, Zb16, S);
    zgemm_mfma<<<dim3(NT128), dim3(512), 0, stream>>>(Zb16, e1b, wf2, rel2_b, S, e2b, NN);

    // ---- output head (bf16 features, single pass) ----
    head_mfma<<<dim3(NT128), dim3(512), 0, stream>>>(e0b, e1b, e2b, hf,
                                                     out0_b, out1_b, out2_b, out, NN);
}

// Round 21
// 202.784 us; speedup vs baseline: 1.0330x; 1.0330x over previous
//
#include <hip/hip_runtime.h>
#include <cstdint>
#include <cstddef>

#define NN 50000
#define NE 800000
#define RREL 5
#define NR (NN * RREL)                 // 250000 (dst,type) keys
#define NB5 ((NR + 255) / 256)         // 977

typedef __attribute__((ext_vector_type(8))) short short8;   // 8 bf16 (4 VGPRs)
typedef __attribute__((ext_vector_type(4))) float f32x4;
typedef unsigned short ushort_t;

static __device__ __forceinline__ float lrelu(float v) { return v > 0.f ? v : 0.01f * v; }

static __device__ __forceinline__ unsigned short f32_bf16_rn(float x) {
    unsigned u = __float_as_uint(x);
    return (unsigned short)((u + 0x7FFFu + ((u >> 16) & 1u)) >> 16);
}
static __device__ __forceinline__ float bf16_f32(unsigned short h) {
    return __uint_as_float(((unsigned)h) << 16);
}

// split 8 f32 (two float4) into bf16 hi + lo (x ~= hi + lo)
static __device__ __forceinline__ void split8v(float4 q0, float4 q1, short8& hi, short8& lo) {
    float v[8] = {q0.x, q0.y, q0.z, q0.w, q1.x, q1.y, q1.z, q1.w};
    #pragma unroll
    for (int j = 0; j < 8; ++j) {
        unsigned short h = f32_bf16_rn(v[j]);
        float hf = __uint_as_float(((unsigned)h) << 16);
        unsigned short l = f32_bf16_rn(v[j] - hf);
        hi[j] = (short)h; lo[j] = (short)l;
    }
}

static __device__ __forceinline__ short8 zero8() {
    short8 z = {0, 0, 0, 0, 0, 0, 0, 0};
    return z;
}

// ---------------------------------------------------------------------------
// zero_deg5: fast workspace zeroing
// ---------------------------------------------------------------------------
__launch_bounds__(256)
__global__ void zero_deg5(int4* __restrict__ p, int n4)
{
    int i = blockIdx.x * 256 + threadIdx.x;
    int stride = gridDim.x * 256;
    for (; i < n4; i += stride)
        p[i] = make_int4(0, 0, 0, 0);
}

// ---------------------------------------------------------------------------
// lin_mfma: e0b = bf16(x @ field_W + field_b)  (K=128)
// ---------------------------------------------------------------------------
__launch_bounds__(512)
__global__ void lin_mfma(const float* __restrict__ X,
                         const short8* __restrict__ ff,   // [16][64] hi frags
                         const float* __restrict__ bias,
                         ushort_t* __restrict__ Cb, int M)
{
    __shared__ short8 wl[16 * 64];   // 16 KB

    const int t = threadIdx.x;
    const int wid = t >> 6, lane = t & 63;
    const int lc = lane & 15, lg = lane >> 4;
    const int row0 = blockIdx.x * 128 + wid * 16;

    const int nA = row0 + lc;
    const bool okA = (nA < M);
    const int nodeA = okA ? nA : 0;

    wl[t] = ff[t];
    wl[t + 512] = ff[t + 512];

    short8 ah[4], al[4];
    #pragma unroll
    for (int s = 0; s < 4; ++s) {
        const float* p = &X[(size_t)nodeA * 128 + s * 32 + lg * 8];
        float4 q0 = okA ? *(const float4*)p       : make_float4(0,0,0,0);
        float4 q1 = okA ? *(const float4*)(p + 4) : make_float4(0,0,0,0);
        split8v(q0, q1, ah[s], al[s]);
    }
    __syncthreads();

    f32x4 acc[4];
    #pragma unroll
    for (int nf = 0; nf < 4; ++nf) acc[nf] = (f32x4){0.f, 0.f, 0.f, 0.f};

    #pragma unroll
    for (int s = 0; s < 4; ++s)
        #pragma unroll
        for (int nf = 0; nf < 4; ++nf) {
            short8 bh = wl[(s * 4 + nf) * 64 + lane];
            acc[nf] = __builtin_amdgcn_mfma_f32_16x16x32_bf16(ah[s], bh, acc[nf], 0, 0, 0);
            acc[nf] = __builtin_amdgcn_mfma_f32_16x16x32_bf16(al[s], bh, acc[nf], 0, 0, 0);
        }

    float bb[4];
    #pragma unroll
    for (int nf = 0; nf < 4; ++nf) bb[nf] = bias[nf * 16 + lc];

    #pragma unroll
    for (int i = 0; i < 4; ++i) {
        int nd = row0 + lg * 4 + i;
        if (nd >= M) continue;
        #pragma unroll
        for (int nf = 0; nf < 4; ++nf)
            Cb[(size_t)nd * 64 + nf * 16 + lc] = f32_bf16_rn(acc[nf][i] + bb[nf]);
    }
}

// ---------------------------------------------------------------------------
// head_mfma: out = sum_src lrelu(Eb_src @ W_src + b_src)
// ---------------------------------------------------------------------------
__launch_bounds__(512)
__global__ void head_mfma(const ushort_t* __restrict__ E0, const ushort_t* __restrict__ E1,
                          const ushort_t* __restrict__ E2,
                          const short8* __restrict__ hf,   // [3][8][64] hi frags
                          const float* __restrict__ b0, const float* __restrict__ b1,
                          const float* __restrict__ b2,
                          float* __restrict__ out, int M)
{
    __shared__ short8 wl[24 * 64];   // 24 KB

    const int t = threadIdx.x;
    const int wid = t >> 6, lane = t & 63;
    const int lc = lane & 15, lg = lane >> 4;
    const int row0 = blockIdx.x * 128 + wid * 16;

    const int nA = row0 + lc;
    const bool okA = (nA < M);
    const int nodeA = okA ? nA : 0;

    wl[t] = hf[t];
    wl[t + 512] = hf[t + 512];
    wl[t + 1024] = hf[t + 1024];

    const ushort_t* Es[3] = {E0, E1, E2};
    const float* bs[3] = {b0, b1, b2};

    float facc[4][4] = {};   // [nf][i]
    __syncthreads();

    #pragma unroll
    for (int src = 0; src < 3; ++src) {
        short8 ah[2];
        #pragma unroll
        for (int s = 0; s < 2; ++s) {
            const ushort_t* p = &Es[src][(size_t)nodeA * 64 + s * 32 + lg * 8];
            ah[s] = okA ? *(const short8*)p : zero8();
        }
        f32x4 acc[4];
        #pragma unroll
        for (int nf = 0; nf < 4; ++nf) acc[nf] = (f32x4){0.f, 0.f, 0.f, 0.f};
        #pragma unroll
        for (int s = 0; s < 2; ++s)
            #pragma unroll
            for (int nf = 0; nf < 4; ++nf) {
                short8 bh = wl[((src * 2 + s) * 4 + nf) * 64 + lane];
                acc[nf] = __builtin_amdgcn_mfma_f32_16x16x32_bf16(ah[s], bh, acc[nf], 0, 0, 0);
            }
        float bb[4];
        #pragma unroll
        for (int nf = 0; nf < 4; ++nf) bb[nf] = bs[src][nf * 16 + lc];
        #pragma unroll
        for (int nf = 0; nf < 4; ++nf)
            #pragma unroll
            for (int i = 0; i < 4; ++i)
                facc[nf][i] += lrelu(acc[nf][i] + bb[nf]);
    }

    #pragma unroll
    for (int i = 0; i < 4; ++i) {
        int nd = row0 + lg * 4 + i;
        if (nd >= M) continue;
        #pragma unroll
        for (int nf = 0; nf < 4; ++nf)
            out[(size_t)nd * 64 + nf * 16 + lc] = facc[nf][i];
    }
}

// ---------------------------------------------------------------------------
// zgather v9 (best measured): TWO nodes per wave (one per 32-lane half).
// Each half walks its own node's full edge range, 8 edges in flight
// (16/wave), features as 32x uint (2 bf16 each). w-sum replicated -> no
// reduction needed.
// ---------------------------------------------------------------------------
__launch_bounds__(256)
__global__ void zgather(const int* __restrict__ offs5,
                        const unsigned long long* __restrict__ epack,
                        const ushort_t* __restrict__ Eb,
                        ushort_t* __restrict__ Zb16, float* __restrict__ S)
{
    int gw = (blockIdx.x * 256 + threadIdx.x) >> 6;   // wave id
    int lane = threadIdx.x & 63;
    const int h = lane >> 5;       // half: 0 or 1
    const int fl = lane & 31;      // uint feature index (2 bf16)
    int node = gw * 2 + h;
    if (node >= NN) return;
    const int b = node * RREL;

    int p    = offs5[b];
    int n1   = offs5[b + 1];
    int n2   = offs5[b + 2];
    int n3   = offs5[b + 3];
    int n4   = offs5[b + 4];
    int pend = offs5[b + 5];

    const unsigned* Ebu = (const unsigned*)Eb;   // feature row = 32 uints
    unsigned* Zu = (unsigned*)Zb16;              // Z segment row = 32 uints
    const int INFP = 0x7fffffff;

    int r = 0;
    float zA0 = 0.f, zA1 = 0.f, zB0 = 0.f, zB1 = 0.f;
    float swA = 0.f, swB = 0.f;

#define SRCI(q) ((unsigned)(q))
#define WVAL(q) __uint_as_float((unsigned)((q) >> 32))

#define FLUSH_CHECK(pe)                                                     \
    while (r < 4 && (pe) == n1) {                                           \
        Zu[(size_t)(b + r) * 32 + fl] =                                     \
            ((unsigned)f32_bf16_rn(zA1 + zB1) << 16) | f32_bf16_rn(zA0 + zB0); \
        if (fl == 0) S[b + r] = swA + swB;                                  \
        zA0 = zA1 = zB0 = zB1 = 0.f; swA = swB = 0.f;                       \
        ++r; n1 = n2; n2 = n3; n3 = n4; n4 = INFP;                          \
    }

#define ACC_A(q, fv)                                                        \
    {                                                                       \
        float w = WVAL(q);                                                  \
        zA0 = fmaf(w, __uint_as_float((fv) << 16), zA0);                    \
        zA1 = fmaf(w, __uint_as_float((fv) & 0xFFFF0000u), zA1);            \
        swA += w;                                                           \
    }
#define ACC_B(q, fv)                                                        \
    {                                                                       \
        float w = WVAL(q);                                                  \
        zB0 = fmaf(w, __uint_as_float((fv) << 16), zB0);                    \
        zB1 = fmaf(w, __uint_as_float((fv) & 0xFFFF0000u), zB1);            \
        swB += w;                                                           \
    }

    for (; p + 8 <= pend; p += 8) {
        unsigned long long q0 = epack[p + 0];
        unsigned long long q1 = epack[p + 1];
        unsigned long long q2 = epack[p + 2];
        unsigned long long q3 = epack[p + 3];
        unsigned long long q4 = epack[p + 4];
        unsigned long long q5 = epack[p + 5];
        unsigned long long q6 = epack[p + 6];
        unsigned long long q7 = epack[p + 7];
        unsigned f0 = Ebu[(size_t)SRCI(q0) * 32 + fl];
        unsigned f1 = Ebu[(size_t)SRCI(q1) * 32 + fl];
        unsigned f2 = Ebu[(size_t)SRCI(q2) * 32 + fl];
        unsigned f3 = Ebu[(size_t)SRCI(q3) * 32 + fl];
        unsigned f4 = Ebu[(size_t)SRCI(q4) * 32 + fl];
        unsigned f5 = Ebu[(size_t)SRCI(q5) * 32 + fl];
        unsigned f6 = Ebu[(size_t)SRCI(q6) * 32 + fl];
        unsigned f7 = Ebu[(size_t)SRCI(q7) * 32 + fl];

        FLUSH_CHECK(p + 0); ACC_A(q0, f0);
        FLUSH_CHECK(p + 1); ACC_B(q1, f1);
        FLUSH_CHECK(p + 2); ACC_A(q2, f2);
        FLUSH_CHECK(p + 3); ACC_B(q3, f3);
        FLUSH_CHECK(p + 4); ACC_A(q4, f4);
        FLUSH_CHECK(p + 5); ACC_B(q5, f5);
        FLUSH_CHECK(p + 6); ACC_A(q6, f6);
        FLUSH_CHECK(p + 7); ACC_B(q7, f7);
    }
    for (; p < pend; ++p) {
        unsigned long long q = epack[p];
        unsigned fv = Ebu[(size_t)SRCI(q) * 32 + fl];
        FLUSH_CHECK(p);
        ACC_A(q, fv);
    }
    while (r < RREL) {
        Zu[(size_t)(b + r) * 32 + fl] =
            ((unsigned)f32_bf16_rn(zA1 + zB1) << 16) | f32_bf16_rn(zA0 + zB0);
        if (fl == 0) S[b + r] = swA + swB;
        zA0 = zA1 = zB0 = zB1 = 0.f; swA = swB = 0.f;
        ++r;
    }
#undef FLUSH_CHECK
#undef ACC_A
#undef ACC_B
#undef SRCI
#undef WVAL
}

// ---------------------------------------------------------------------------
// prep_wfrag: weight fragment prep (rel hi+lo; field hi; head hi).
// ---------------------------------------------------------------------------
__launch_bounds__(256)
__global__ void prep_wfrag(const float* __restrict__ rel1_W, const float* __restrict__ rel2_W,
                           const float* __restrict__ field_W,
                           const float* __restrict__ out0_W, const float* __restrict__ out1_W,
                           const float* __restrict__ out2_W,
                           short8* __restrict__ wf1, short8* __restrict__ wf2,
                           short8* __restrict__ ff, short8* __restrict__ hf)
{
    int bid = blockIdx.x;
    int t = threadIdx.x;

    if (bid < 20) {
        int layer = bid / 10, c = bid % 10;
        const float* relW = layer ? rel2_W : rel1_W;
        short8* wf = layer ? wf2 : wf1;
        for (int sl = t; sl < 512; sl += 256) {
            int rid = sl >> 6, lane = sl & 63;
            int s = rid >> 2, nf = rid & 3;
            int g = lane >> 4, lc = lane & 15;
            int r = (c < 5) ? c : c - 5;
            const float* W = relW + (size_t)r * 8192 + ((c < 5) ? 0 : 4096);
            float v[8];
            #pragma unroll
            for (int j = 0; j < 8; ++j)
                v[j] = W[(size_t)(s * 32 + g * 8 + j) * 64 + nf * 16 + lc];
            float4 q0 = make_float4(v[0], v[1], v[2], v[3]);
            float4 q1 = make_float4(v[4], v[5], v[6], v[7]);
            short8 hi, lo;
            split8v(q0, q1, hi, lo);
            size_t slot = (size_t)c * 1024 + (size_t)((s * 4 + nf) * 64 + lane) * 2;
            wf[slot]     = hi;
            wf[slot + 1] = lo;
        }
    } else if (bid < 24) {
        int s = bid - 20;             // K-slice 0..3
        for (int sl = t; sl < 256; sl += 256) {
            int nf = sl >> 6, lane = sl & 63;
            int g = lane >> 4, lc = lane & 15;
            float v[8];
            #pragma unroll
            for (int j = 0; j < 8; ++j)
                v[j] = field_W[(size_t)(s * 32 + g * 8 + j) * 64 + nf * 16 + lc];
            short8 hi;
            #pragma unroll
            for (int j = 0; j < 8; ++j) hi[j] = (short)f32_bf16_rn(v[j]);
            ff[(size_t)(s * 4 + nf) * 64 + lane] = hi;
        }
    } else {
        int hsrc = bid - 24;          // 0..2
        const float* W = (hsrc == 0) ? out0_W : (hsrc == 1) ? out1_W : out2_W;
        for (int sl = t; sl < 512; sl += 256) {
            int rid = sl >> 6, lane = sl & 63;
            int s = rid >> 2, nf = rid & 3;
            if (s >= 2) continue;
            int g = lane >> 4, lc = lane & 15;
            float v[8];
            #pragma unroll
            for (int j = 0; j < 8; ++j)
                v[j] = W[(size_t)(s * 32 + g * 8 + j) * 64 + nf * 16 + lc];
            short8 hi;
            #pragma unroll
            for (int j = 0; j < 8; ++j) hi[j] = (short)f32_bf16_rn(v[j]);
            hf[(size_t)((hsrc * 2 + s) * 4 + nf) * 64 + lane] = hi;
        }
    }
}

// ---------------------------------------------------------------------------
// zgemm_mfma v4: all-bf16 features; Z + e_prev direct fragments.
// ---------------------------------------------------------------------------
__launch_bounds__(512)
__global__ void zgemm_mfma(const ushort_t* __restrict__ Zb16,
                           const ushort_t* __restrict__ EbPrev,
                           const short8* __restrict__ wf,
                           const float* __restrict__ relb,
                           const float* __restrict__ S,
                           ushort_t* __restrict__ Enb, int M)
{
    __shared__ short8 wlds[2][1024];   // 2 x 16 KB

    const int t = threadIdx.x;
    const int wid = t >> 6, lane = t & 63;
    const int lc = lane & 15, lg = lane >> 4;
    const int row0 = blockIdx.x * 128 + wid * 16;

    const int nA = row0 + lc;
    const bool okA = (nA < M);
    const int nodeA = okA ? nA : 0;

    const int sq = t >> 6, sl = t & 63;
    const int wrA = (sq * 2 + 0) * 64 + sl;
    const int wrB = (sq * 2 + 1) * 64 + sl;

    short8 eh[2];
    #pragma unroll
    for (int s = 0; s < 2; ++s) {
        const ushort_t* p = &EbPrev[(size_t)nodeA * 64 + s * 32 + lg * 8];
        eh[s] = okA ? *(const short8*)p : zero8();
    }

    float sD[4][RREL];
    #pragma unroll
    for (int i = 0; i < 4; ++i) {
        int nd = row0 + lg * 4 + i;
        int ns = (nd < M) ? nd : 0;
        #pragma unroll
        for (int r = 0; r < RREL; ++r)
            sD[i][r] = S[(size_t)ns * RREL + r];
    }

    {
        const short8* wp = wf + (size_t)t * 2;
        short8 sa = wp[0], sb = wp[1];
        wlds[0][wrA] = sa; wlds[0][wrB] = sb;
    }
    short8 az0, az1;
    {
        const ushort_t* zb = &Zb16[(size_t)nodeA * 320 + lg * 8];
        az0 = okA ? *(const short8*)(zb)      : zero8();
        az1 = okA ? *(const short8*)(zb + 32) : zero8();
    }
    __syncthreads();

    f32x4 acc[4];
    #pragma unroll
    for (int nf = 0; nf < 4; ++nf) acc[nf] = (f32x4){0.f, 0.f, 0.f, 0.f};

    short8 sreg_a, sreg_b;
    short8 pz0, pz1;

    #pragma unroll
    for (int c = 0; c < 10; ++c) {
        const int cb = c & 1;
        if (c < 9) {
            const short8* wp = wf + (size_t)(c + 1) * 1024 + (size_t)t * 2;
            sreg_a = wp[0]; sreg_b = wp[1];
        }
        if (c < 4) {
            const ushort_t* zb = &Zb16[(size_t)nodeA * 320 + (c + 1) * 64 + lg * 8];
            pz0 = okA ? *(const short8*)(zb)      : zero8();
            pz1 = okA ? *(const short8*)(zb + 32) : zero8();
        }

        if (c < 5) {
            #pragma unroll
            for (int s = 0; s < 2; ++s) {
                short8 Az = (s == 0) ? az0 : az1;
                #pragma unroll
                for (int nf = 0; nf < 4; ++nf) {
                    short8 bh = wlds[cb][((s * 4 + nf) * 2 + 0) * 64 + lane];
                    short8 bl = wlds[cb][((s * 4 + nf) * 2 + 1) * 64 + lane];
                    acc[nf] = __builtin_amdgcn_mfma_f32_16x16x32_bf16(Az, bh, acc[nf], 0, 0, 0);
                    acc[nf] = __builtin_amdgcn_mfma_f32_16x16x32_bf16(Az, bl, acc[nf], 0, 0, 0);
                }
            }
        } else {
            f32x4 tmp[4];
            #pragma unroll
            for (int nf = 0; nf < 4; ++nf) tmp[nf] = (f32x4){0.f, 0.f, 0.f, 0.f};
            #pragma unroll
            for (int s = 0; s < 2; ++s)
                #pragma unroll
                for (int nf = 0; nf < 4; ++nf) {
                    short8 bh = wlds[cb][((s * 4 + nf) * 2 + 0) * 64 + lane];
                    short8 bl = wlds[cb][((s * 4 + nf) * 2 + 1) * 64 + lane];
                    tmp[nf] = __builtin_amdgcn_mfma_f32_16x16x32_bf16(eh[s], bh, tmp[nf], 0, 0, 0);
                    tmp[nf] = __builtin_amdgcn_mfma_f32_16x16x32_bf16(eh[s], bl, tmp[nf], 0, 0, 0);
                }
            const int r = c - 5;
            #pragma unroll
            for (int nf = 0; nf < 4; ++nf)
                #pragma unroll
                for (int i = 0; i < 4; ++i)
                    acc[nf][i] += sD[i][r] * tmp[nf][i];
        }

        if (c < 4) { az0 = pz0; az1 = pz1; }

        if (c < 9) {
            __syncthreads();
            wlds[cb ^ 1][wrA] = sreg_a;
            wlds[cb ^ 1][wrB] = sreg_b;
            __syncthreads();
        }
    }

    float bbv[4][RREL];
    #pragma unroll
    for (int nf = 0; nf < 4; ++nf)
        #pragma unroll
        for (int r = 0; r < RREL; ++r)
            bbv[nf][r] = relb[r * 64 + nf * 16 + lc];

    #pragma unroll
    for (int i = 0; i < 4; ++i) {
        int nd = row0 + lg * 4 + i;
        if (nd >= M) continue;
        #pragma unroll
        for (int nf = 0; nf < 4; ++nf) {
            float v = acc[nf][i];
            #pragma unroll
            for (int r = 0; r < RREL; ++r)
                v += sD[i][r] * bbv[nf][r];
            Enb[(size_t)nd * 64 + nf * 16 + lc] = f32_bf16_rn(v);
        }
    }
}

// ---------------------------------------------------------------------------
// CSR build over (dst,type) keys
// ---------------------------------------------------------------------------
__launch_bounds__(256)
__global__ void deg5_hist(const int* __restrict__ dst, const int* __restrict__ etype,
                          int* __restrict__ deg5, int* __restrict__ slot5)
{
    int e = blockIdx.x * 256 + threadIdx.x;
    if (e < NE) slot5[e] = atomicAdd(&deg5[dst[e] * RREL + etype[e]], 1);
}

__launch_bounds__(256)
__global__ void b1_reduce(const int* __restrict__ deg5, int* __restrict__ b1)
{
    __shared__ int sh[256];
    int i = blockIdx.x * 256 + threadIdx.x;
    sh[threadIdx.x] = (i < NR) ? deg5[i] : 0;
    __syncthreads();
    for (int s = 128; s > 0; s >>= 1) {
        if (threadIdx.x < s) sh[threadIdx.x] += sh[threadIdx.x + s];
        __syncthreads();
    }
    if (threadIdx.x == 0) b1[blockIdx.x] = sh[0];
}

__launch_bounds__(256)
__global__ void scan_seq(int* __restrict__ b1, int n)
{
    __shared__ int sh[256];
    __shared__ int carry;
    if (threadIdx.x == 0) carry = 0;
    __syncthreads();
    for (int base = 0; base < n; base += 256) {
        int i = base + threadIdx.x;
        int v = (i < n) ? b1[i] : 0;
        sh[threadIdx.x] = v;
        __syncthreads();
        for (int off = 1; off < 256; off <<= 1) {
            int x = (threadIdx.x >= off) ? sh[threadIdx.x - off] : 0;
            __syncthreads();
            sh[threadIdx.x] += x;
            __syncthreads();
        }
        int excl = sh[threadIdx.x] - v + carry;
        if (i < n) b1[i] = excl;
        __syncthreads();
        if (threadIdx.x == 255) carry = excl + v;
        __syncthreads();
    }
}

__launch_bounds__(256)
__global__ void offs5_final(const int* __restrict__ deg5, const int* __restrict__ b1,
                            int* __restrict__ offs5)
{
    __shared__ int sh[256];
    int t = threadIdx.x;
    int i = blockIdx.x * 256 + t;
    int v = (i < NR) ? deg5[i] : 0;
    sh[t] = v;
    __syncthreads();
    for (int off = 1; off < 256; off <<= 1) {
        int x = (t >= off) ? sh[t - off] : 0;
        __syncthreads();
        sh[t] += x;
        __syncthreads();
    }
    int excl = sh[t] - v + b1[blockIdx.x];
    if (i <= NR) offs5[i] = excl;
}

// scatter: epack[offs5[dst*5+r] + slot5[e]] = {w, src} packed u64
__launch_bounds__(256)
__global__ void scatter_pass(const int* __restrict__ src, const int* __restrict__ dst,
                             const int* __restrict__ etype,
                             const float* __restrict__ etime,
                             const float* __restrict__ beta,
                             const float* __restrict__ lambda_p,
                             const int* __restrict__ slot5, const int* __restrict__ offs5,
                             unsigned long long* __restrict__ epack)
{
    int e = blockIdx.x * 256 + threadIdx.x;
    if (e >= NE) return;
    float b[12];
    #pragma unroll
    for (int j = 0; j < 12; ++j) b[j] = beta[j];
    const float* et = etime + (size_t)e * 12;
    float4 v0 = *(const float4*)(et);
    float4 v1 = *(const float4*)(et + 4);
    float4 v2 = *(const float4*)(et + 8);
    float logit = v0.x*b[0] + v0.y*b[1] + v0.z*b[2] + v0.w*b[3]
                + v1.x*b[4] + v1.y*b[5] + v1.z*b[6] + v1.w*b[7]
                + v2.x*b[8] + v2.y*b[9] + v2.z*b[10] + v2.w*b[11];
    float we = lambda_p[0] * expf(-logit);
    int p = offs5[dst[e] * RREL + etype[e]] + slot5[e];
    epack[p] = ((unsigned long long)__float_as_uint(we) << 32) | (unsigned)src[e];
}

// ---------------------------------------------------------------------------
extern "C" void kernel_launch(void* const* d_in, const int* in_sizes, int n_in,
                              void* d_out, int out_size, void* d_ws, size_t ws_size,
                              hipStream_t stream)
{
    const float* x        = (const float*)d_in[0];
    const int*   eidx     = (const int*)d_in[1];
    const int*   etype    = (const int*)d_in[2];
    const float* etime    = (const float*)d_in[3];
    const float* lambda_p = (const float*)d_in[4];
    const float* beta     = (const float*)d_in[5];
    const float* field_W  = (const float*)d_in[6];
    const float* field_b  = (const float*)d_in[7];
    const float* rel1_W   = (const float*)d_in[8];
    const float* rel1_b   = (const float*)d_in[9];
    const float* rel2_W   = (const float*)d_in[10];
    const float* rel2_b   = (const float*)d_in[11];
    const float* out0_W   = (const float*)d_in[12];
    const float* out0_b   = (const float*)d_in[13];
    const float* out1_W   = (const float*)d_in[14];
    const float* out1_b   = (const float*)d_in[15];
    const float* out2_W   = (const float*)d_in[16];
    const float* out2_b   = (const float*)d_in[17];
    const int* src = eidx;
    const int* dst = eidx + NE;
    float* out = (float*)d_out;

    char* wsb = (char*)d_ws;
    size_t off = 0;
    auto carve = [&](size_t bytes) -> void* {
        void* p = (void*)(wsb + off);
        off += (bytes + 255) & ~(size_t)255;
        return p;
    };
    int*   deg5   = (int*)carve((size_t)NR * 4);            // 1 MB
    int*   offs5  = (int*)carve((size_t)(NR + 1) * 4);      // 1 MB
    int*   b1     = (int*)carve((size_t)NB5 * 4);
    int*   slot5  = (int*)carve((size_t)NE * 4);            // 3.2 MB
    float* S      = (float*)carve((size_t)NR * 4);          // 1 MB
    unsigned long long* epack = (unsigned long long*)carve((size_t)NE * 8); // 6.4 MB
    ushort_t* e0b = (ushort_t*)carve((size_t)NN * 64 * 2);  // 6.4 MB bf16
    ushort_t* e1b = (ushort_t*)carve((size_t)NN * 64 * 2);  // 6.4 MB bf16
    ushort_t* e2b = (ushort_t*)carve((size_t)NN * 64 * 2);  // 6.4 MB bf16
    ushort_t* Zb16 = (ushort_t*)carve((size_t)NN * 320 * 2); // 32 MB bf16 Z
    short8* wf1   = (short8*)carve((size_t)20 * 16384);     // 320 KB
    short8* wf2   = (short8*)carve((size_t)20 * 16384);     // 320 KB
    short8* ff    = (short8*)carve((size_t)16 * 64 * 16);   // 16 KB field frags
    short8* hf    = (short8*)carve((size_t)24 * 64 * 16);   // 24 KB head frags

    dim3 blk(256);
    const int NT128 = (NN + 127) / 128;     // 391
    const int EB = (NE + 255) / 256;
    const int GB2 = (((NN + 1) / 2) * 64 + 255) / 256;   // two nodes per wave

    // ---- CSR build over (dst,type) + weight frag prep ----
    zero_deg5<<<256, blk, 0, stream>>>((int4*)deg5, (NR + 3) / 4);
    deg5_hist<<<EB, blk, 0, stream>>>(dst, etype, deg5, slot5);
    prep_wfrag<<<27, blk, 0, stream>>>(rel1_W, rel2_W, field_W, out0_W, out1_W, out2_W,
                                       wf1, wf2, ff, hf);
    b1_reduce<<<NB5, blk, 0, stream>>>(deg5, b1);
    scan_seq<<<1, blk, 0, stream>>>(b1, NB5);
    offs5_final<<<NB5, blk, 0, stream>>>(deg5, b1, offs5);
    scatter_pass<<<EB, blk, 0, stream>>>(src, dst, etype, etime, beta, lambda_p,
                                         slot5, offs5, epack);

    // ---- e0b = bf16(x @ field_W + field_b) ----
    lin_mfma<<<dim3(NT128), dim3(512), 0, stream>>>(x, ff, field_b, e0b, NN);

    // ---- layer 1 ----
    zgather<<<GB2, blk, 0, stream>>>(offs5, epack, e0b, Zb16, S);
    zgemm_mfma<<<dim3(NT128), dim3(512), 0, stream>>>(Zb16, e0b, wf1, rel1_b, S, e1b, NN);

    // ---- layer 2 ----
    zgather<<<GB2, blk, 0, stream>>>(offs5, epack, e1b, Zb16, S);
    zgemm_mfma<<<dim3(NT128), dim3(512), 0, stream>>>(Zb16, e1b, wf2, rel2_b, S, e2b, NN);

    // ---- output head (bf16 features, single pass) ----
    head_mfma<<<dim3(NT128), dim3(512), 0, stream>>>(e0b, e1b, e2b, hf,
                                                     out0_b, out1_b, out2_b, out, NN);
}